// Round 1
// baseline (636.433 us; speedup 1.0000x reference)
//
#include <hip/hip_runtime.h>

// MergedEmbeddingBag forward: sum-pool, T tables merged.
// weights: [T, N, D] f32, indices: [T, TOTAL] i32, offsets: [T, B] i32
// out: [T, B, D] f32
#define T_TABLES 8
#define N_ROWS   100000
#define DIM      128
#define BAGS     16384
#define TOTAL_IDX (BAGS * 20)

#define DV (DIM / 4)   // float4 chunks per row = 32

__global__ __launch_bounds__(256) void merged_embbag_kernel(
    const float4* __restrict__ weights,
    const int*    __restrict__ indices,
    const int*    __restrict__ offsets,
    float4*       __restrict__ out)
{
    int gid = blockIdx.x * blockDim.x + threadIdx.x;   // [0, T*B*DV)
    int c  = gid & (DV - 1);        // float4 column within row
    int tb = gid >> 5;              // table*B + bag  (DV == 32)
    int b  = tb & (BAGS - 1);
    int t  = tb >> 14;              // BAGS == 16384 == 2^14

    const int* off = offsets + t * BAGS;
    int start = off[b];
    int end   = (b == BAGS - 1) ? TOTAL_IDX : off[b + 1];

    const int* idx = indices + (size_t)t * TOTAL_IDX;
    const float4* w = weights + (size_t)t * N_ROWS * DV;

    float4 acc = make_float4(0.f, 0.f, 0.f, 0.f);
    for (int p = start; p < end; ++p) {
        int row = idx[p];
        float4 v = w[(size_t)row * DV + c];
        acc.x += v.x; acc.y += v.y; acc.z += v.z; acc.w += v.w;
    }
    out[gid] = acc;
}

extern "C" void kernel_launch(void* const* d_in, const int* in_sizes, int n_in,
                              void* d_out, int out_size, void* d_ws, size_t ws_size,
                              hipStream_t stream) {
    const float4* weights = (const float4*)d_in[0];
    const int*    indices = (const int*)d_in[1];
    const int*    offsets = (const int*)d_in[2];
    float4*       out     = (float4*)d_out;

    const int total_threads = T_TABLES * BAGS * DV;   // 4,194,304
    const int block = 256;
    const int grid  = (total_threads + block - 1) / block;
    merged_embbag_kernel<<<grid, block, 0, stream>>>(weights, indices, offsets, out);
}

// Round 2
// 614.959 us; speedup vs baseline: 1.0349x; 1.0349x over previous
//
#include <hip/hip_runtime.h>

// MergedEmbeddingBag forward: sum-pool, T tables merged.
// weights: [T, N, D] f32, indices: [T, TOTAL] i32, offsets: [T, B] i32
// out: [T, B, D] f32
#define T_TABLES 8
#define N_ROWS   100000
#define DIM      128
#define BAGS     16384
#define BAG_L    20
#define TOTAL_IDX (BAGS * BAG_L)

#define DV (DIM / 4)   // float4 chunks per row = 32

__global__ __launch_bounds__(256) void merged_embbag_kernel(
    const float4* __restrict__ weights,
    const int*    __restrict__ indices,
    const int*    __restrict__ offsets,
    float4*       __restrict__ out)
{
    int gid = blockIdx.x * blockDim.x + threadIdx.x;   // [0, T*B*DV)
    int c  = gid & (DV - 1);        // float4 column within row
    int tb = gid >> 5;              // table*B + bag  (DV == 32)
    int b  = tb & (BAGS - 1);
    int t  = tb >> 14;              // BAGS == 16384 == 2^14

    const int* off = offsets + t * BAGS;
    int start = off[b];
    int end   = (b == BAGS - 1) ? TOTAL_IDX : off[b + 1];
    int n = end - start;

    const int*    idx = indices + (size_t)t * TOTAL_IDX + start;
    const float4* w   = weights + (size_t)t * N_ROWS * DV + c;

    float4 acc = make_float4(0.f, 0.f, 0.f, 0.f);

    if (n == BAG_L) {
        // Fast path: compile-time trip count -> all index loads issued up
        // front, then all 20 gathers in flight before the accumulate chain.
        int rows[BAG_L];
        #pragma unroll
        for (int j = 0; j < BAG_L; ++j) rows[j] = idx[j];

        float4 v[BAG_L];
        #pragma unroll
        for (int j = 0; j < BAG_L; ++j) v[j] = w[(size_t)rows[j] * DV];

        #pragma unroll
        for (int j = 0; j < BAG_L; ++j) {
            acc.x += v[j].x; acc.y += v[j].y; acc.z += v[j].z; acc.w += v[j].w;
        }
    } else {
        // General fallback: arbitrary bag sizes (EmbeddingBag semantics).
        for (int p = 0; p < n; ++p) {
            int row = idx[p];
            float4 v = w[(size_t)row * DV];
            acc.x += v.x; acc.y += v.y; acc.z += v.z; acc.w += v.w;
        }
    }

    out[gid] = acc;
}

extern "C" void kernel_launch(void* const* d_in, const int* in_sizes, int n_in,
                              void* d_out, int out_size, void* d_ws, size_t ws_size,
                              hipStream_t stream) {
    const float4* weights = (const float4*)d_in[0];
    const int*    indices = (const int*)d_in[1];
    const int*    offsets = (const int*)d_in[2];
    float4*       out     = (float4*)d_out;

    const int total_threads = T_TABLES * BAGS * DV;   // 4,194,304
    const int block = 256;
    const int grid  = (total_threads + block - 1) / block;
    merged_embbag_kernel<<<grid, block, 0, stream>>>(weights, indices, offsets, out);
}